// Round 7
// baseline (384.853 us; speedup 1.0000x reference)
//
#include <hip/hip_runtime.h>

#define B_  2
#define N_  4096
#define D_  512
#define H_  8
#define HD_ 64
// (D^-0.5) * log2(e): fold softmax scale AND exp->exp2 conversion into Q
#define SCL2 (0.04419417382415922f * 1.4426950408889634f)

typedef float  f32x4  __attribute__((ext_vector_type(4)));
typedef float  f32x16 __attribute__((ext_vector_type(16)));
typedef short  s16x8  __attribute__((ext_vector_type(8)));
typedef short  s16x4  __attribute__((ext_vector_type(4)));
typedef unsigned int u32x4 __attribute__((ext_vector_type(4)));

#define MFMA16(a,b,c) __builtin_amdgcn_mfma_f32_16x16x32_bf16((a),(b),(c),0,0,0)
#define MFMA32(a,b,c) __builtin_amdgcn_mfma_f32_32x32x16_bf16((a),(b),(c),0,0,0)

__device__ __forceinline__ unsigned bf16rtn(float x){
    unsigned u = __float_as_uint(x);
    return (u + 0x7FFFu + ((u >> 16) & 1u)) >> 16;
}
__device__ __forceinline__ float bf16tof(unsigned h){
    return __uint_as_float(h << 16);
}
__device__ __forceinline__ unsigned cvt_pk_bf16(float lo, float hi){
    unsigned r;
    asm("v_cvt_pk_bf16_f32 %0, %1, %2" : "=v"(r) : "v"(lo), "v"(hi));
    return r;
}
__device__ __forceinline__ void perm32swap(unsigned &a, unsigned &b){
    asm volatile("v_permlane32_swap_b32 %0, %1" : "+v"(a), "+v"(b));
}
// [*][64] bf16 arrays: XOR-swizzle 8-elem (16B) blocks with row&7
__device__ __forceinline__ int ix16(int r, int c){
    return (r << 6) + ((((c >> 3) ^ (r & 7)) << 3) | (c & 7));
}
// transposed arrays: extra ^(r>>3) so transpose-WRITES spread over 32 banks
__device__ __forceinline__ int ixt(int r, int c){
    return (r << 6) + ((((c >> 3) ^ (r & 7) ^ ((r >> 3) & 7)) << 3) | (c & 7));
}

// ---------------------------------------------------------------------------
// Split pass: fp32 -> (bf16 hi, bf16 lo) for x, Wq, Wk. Pure streaming.
// ---------------------------------------------------------------------------
__global__ __launch_bounds__(256) void split_kernel(
    const float* __restrict__ x, const float* __restrict__ Wq, const float* __restrict__ Wk,
    short* __restrict__ xh, short* __restrict__ xl,
    short* __restrict__ wqh, short* __restrict__ wql,
    short* __restrict__ wkh, short* __restrict__ wkl)
{
    const int bid = blockIdx.x;
    const float* src; short* dh; short* dl; size_t base;
    if (bid < 2048)      { src = x;  dh = xh;  dl = xl;  base = (size_t)bid * 2048; }
    else if (bid < 2176) { src = Wq; dh = wqh; dl = wql; base = (size_t)(bid - 2048) * 2048; }
    else                 { src = Wk; dh = wkh; dl = wkl; base = (size_t)(bid - 2176) * 2048; }

    const size_t off = base + (size_t)threadIdx.x * 8;
    float4 a = *(const float4*)&src[off];
    float4 c = *(const float4*)&src[off + 4];
    float v[8] = {a.x,a.y,a.z,a.w, c.x,c.y,c.z,c.w};
    s16x8 oh, ol;
    #pragma unroll
    for (int j = 0; j < 8; ++j) {
        unsigned hh = bf16rtn(v[j]);
        float lo = v[j] - bf16tof(hh);
        unsigned ll = bf16rtn(lo);
        oh[j] = (short)hh; ol[j] = (short)ll;
    }
    *(s16x8*)&dh[off] = oh;
    *(s16x8*)&dl[off] = ol;
}

// ---------------------------------------------------------------------------
// Projection GEMM on MFMA, bf16x3 split precision. (unchanged)
// ---------------------------------------------------------------------------
__global__ __launch_bounds__(256, 2) void proj_gemm(
    const short* __restrict__ xh, const short* __restrict__ xl,
    const short* __restrict__ wqh, const short* __restrict__ wql,
    const short* __restrict__ wkh, const short* __restrict__ wkl,
    const float* __restrict__ bq, const float* __restrict__ bk,
    float* __restrict__ Qout, short* __restrict__ Khi, short* __restrict__ Klo)
{
    __shared__ short Ah[8192], Al[8192], Bh[8192], Bl[8192];   // [128][64] ix16

    const short* gWh  = blockIdx.z ? wkh : wqh;
    const short* gWl  = blockIdx.z ? wkl : wql;
    const float* bias = blockIdx.z ? bk  : bq;

    const int m0 = blockIdx.x * 128;
    const int e0 = blockIdx.y * 128;
    const int tid = threadIdx.x;
    const int wave = tid >> 6, lane = tid & 63;
    const int lr = lane & 15, lg = lane >> 4;

    int srow[4], scol[4];
    #pragma unroll
    for (int s = 0; s < 4; ++s) {
        int slot = s * 256 + tid;
        srow[s] = slot >> 3;
        scol[s] = (slot & 7) << 3;
    }

    f32x4 acc[2][8] = {};
    s16x8 pah[4], pal[4], pbh[4], pbl[4];

    #pragma unroll
    for (int s = 0; s < 4; ++s) {
        size_t ao = (size_t)(m0 + srow[s]) * D_ + scol[s];
        size_t bo = (size_t)(e0 + srow[s]) * D_ + scol[s];
        pah[s] = *(const s16x8*)&xh[ao];  pal[s] = *(const s16x8*)&xl[ao];
        pbh[s] = *(const s16x8*)&gWh[bo]; pbl[s] = *(const s16x8*)&gWl[bo];
    }

    for (int kt = 0; kt < 8; ++kt) {
        if (kt) __syncthreads();
        #pragma unroll
        for (int s = 0; s < 4; ++s) {
            int d = ix16(srow[s], scol[s]);
            *(s16x8*)&Ah[d] = pah[s];  *(s16x8*)&Al[d] = pal[s];
            *(s16x8*)&Bh[d] = pbh[s];  *(s16x8*)&Bl[d] = pbl[s];
        }
        __syncthreads();
        if (kt < 7) {
            const int k0 = (kt + 1) * 64;
            #pragma unroll
            for (int s = 0; s < 4; ++s) {
                size_t ao = (size_t)(m0 + srow[s]) * D_ + k0 + scol[s];
                size_t bo = (size_t)(e0 + srow[s]) * D_ + k0 + scol[s];
                pah[s] = *(const s16x8*)&xh[ao];  pal[s] = *(const s16x8*)&xl[ao];
                pbh[s] = *(const s16x8*)&gWh[bo]; pbl[s] = *(const s16x8*)&gWl[bo];
            }
        }
        __builtin_amdgcn_s_setprio(1);
        #pragma unroll
        for (int ks = 0; ks < 2; ++ks) {
            s16x8 afh[2], afl[2];
            #pragma unroll
            for (int f = 0; f < 2; ++f) {
                int a = ix16(wave*32 + f*16 + lr, ks*32 + lg*8);
                afh[f] = *(const s16x8*)&Ah[a];
                afl[f] = *(const s16x8*)&Al[a];
            }
            #pragma unroll
            for (int t = 0; t < 8; ++t) {
                int bA = ix16(t*16 + lr, ks*32 + lg*8);
                s16x8 bfh = *(const s16x8*)&Bh[bA];
                s16x8 bfl = *(const s16x8*)&Bl[bA];
                #pragma unroll
                for (int f = 0; f < 2; ++f) {
                    acc[f][t] = MFMA16(afh[f], bfh, acc[f][t]);
                    acc[f][t] = MFMA16(afh[f], bfl, acc[f][t]);
                    acc[f][t] = MFMA16(afl[f], bfh, acc[f][t]);
                }
            }
        }
        __builtin_amdgcn_s_setprio(0);
    }

    float bb[8];
    #pragma unroll
    for (int t = 0; t < 8; ++t) bb[t] = bias[e0 + t*16 + lr];

    if (blockIdx.z == 0) {
        #pragma unroll
        for (int f = 0; f < 2; ++f)
            #pragma unroll
            for (int t = 0; t < 8; ++t)
                #pragma unroll
                for (int r = 0; r < 4; ++r) {
                    int row = m0 + wave*32 + f*16 + lg*4 + r;
                    Qout[(size_t)row * D_ + e0 + t*16 + lr] = acc[f][t][r] + bb[t];
                }
    } else {
        #pragma unroll
        for (int f = 0; f < 2; ++f)
            #pragma unroll
            for (int t = 0; t < 8; ++t)
                #pragma unroll
                for (int r = 0; r < 4; ++r) {
                    int row = m0 + wave*32 + f*16 + lg*4 + r;
                    float v = acc[f][t][r] + bb[t];
                    unsigned hh = bf16rtn(v);
                    float lo = v - bf16tof(hh);
                    unsigned ll = bf16rtn(lo);
                    size_t o = (size_t)row * D_ + e0 + t*16 + lr;
                    Khi[o] = (short)hh;
                    Klo[o] = (short)ll;
                }
    }
}

// ---------------------------------------------------------------------------
// FALLBACK projection (fp32 vector path) — only if ws_size is too small.
// ---------------------------------------------------------------------------
__global__ __launch_bounds__(256) void proj_kernel(
    const float* __restrict__ x,
    const float* __restrict__ Wq, const float* __restrict__ bq,
    const float* __restrict__ Wk, const float* __restrict__ bk,
    float* __restrict__ Qout, short* __restrict__ Khi, short* __restrict__ Klo)
{
    const float* W    = blockIdx.z ? Wk : Wq;
    const float* bias = blockIdx.z ? bk : bq;

    const int m0 = blockIdx.x * 128;
    const int e0 = blockIdx.y * 128;

    __shared__ float Xs[128][36];
    __shared__ float Ws[128 * 36];

    const int tid = threadIdx.x;
    const int tx = tid & 15, ty = tid >> 4;

    float acc[8][8] = {};

    for (int k0 = 0; k0 < D_; k0 += 32) {
        #pragma unroll
        for (int s = 0; s < 4; ++s) {
            int slot = s * 256 + tid;
            int r  = slot >> 3;
            int c4 = (slot & 7) << 2;
            *(float4*)&Xs[r][c4] = *(const float4*)&x[(size_t)(m0 + r) * D_ + k0 + c4];
            int wblk = ((c4 >> 2) ^ (r >> 3)) & 7;
            *(float4*)&Ws[r * 36 + wblk * 4] = *(const float4*)&W[(size_t)(e0 + r) * D_ + k0 + c4];
        }
        __syncthreads();
        #pragma unroll
        for (int k = 0; k < 32; k += 4) {
            float4 xa[8], wb[8];
            #pragma unroll
            for (int i = 0; i < 8; ++i) xa[i] = *(float4*)&Xs[ty*8+i][k];
            #pragma unroll
            for (int j = 0; j < 8; ++j) {
                int row = tx*8 + j;
                int blk = ((k >> 2) ^ (row >> 3)) & 7;
                wb[j] = *(float4*)&Ws[row * 36 + blk * 4];
            }
            #pragma unroll
            for (int i = 0; i < 8; ++i)
                #pragma unroll
                for (int j = 0; j < 8; ++j)
                    acc[i][j] += xa[i].x*wb[j].x + xa[i].y*wb[j].y
                               + xa[i].z*wb[j].z + xa[i].w*wb[j].w;
        }
        __syncthreads();
    }

    const float4 bv0 = *(const float4*)&bias[e0 + tx*8];
    const float4 bv1 = *(const float4*)&bias[e0 + tx*8 + 4];
    const float bj[8] = {bv0.x,bv0.y,bv0.z,bv0.w, bv1.x,bv1.y,bv1.z,bv1.w};

    if (blockIdx.z == 0) {
        #pragma unroll
        for (int i = 0; i < 8; ++i) {
            float o[8];
            #pragma unroll
            for (int j = 0; j < 8; ++j) o[j] = acc[i][j] + bj[j];
            size_t off = (size_t)(m0 + ty*8 + i) * D_ + e0 + tx*8;
            *(float4*)&Qout[off]     = *(float4*)&o[0];
            *(float4*)&Qout[off + 4] = *(float4*)&o[4];
        }
    } else {
        #pragma unroll
        for (int i = 0; i < 8; ++i) {
            s16x8 oh, ol;
            #pragma unroll
            for (int j = 0; j < 8; ++j) {
                float v = acc[i][j] + bj[j];
                unsigned hh = bf16rtn(v);
                float lo = v - bf16tof(hh);
                unsigned ll = bf16rtn(lo);
                oh[j] = (short)hh; ol[j] = (short)ll;
            }
            size_t off = (size_t)(m0 + ty*8 + i) * D_ + e0 + tx*8;
            *(s16x8*)&Khi[off] = oh;
            *(s16x8*)&Klo[off] = ol;
        }
    }
}

// ---------------------------------------------------------------------------
// Flash attention, 32x32x16 MFMA, swapped operands, V = K.
// QBLK=64 (2 waves x 32 q), KVBLK=64, 128-thread blocks for phase diversity.
// SPLIT=1: each block does half the keys, writes partial O^T + (m,l).
// SPLIT=0: full key range, final normalized + transposed store.
// ---------------------------------------------------------------------------
template<int SPLIT>
__global__ __launch_bounds__(128, 4) void attn_kernel(
    const float* __restrict__ Q,
    const short* __restrict__ Khi, const short* __restrict__ Klo,
    float* __restrict__ out, float* __restrict__ Opart, float* __restrict__ Ml)
{
    __shared__ __align__(16) char smem[32768];
    short* Khs  = (short*)smem;          // [64][64] hi  (ix16)
    short* Kls  = Khs + 4096;            // lo
    short* Kths = Kls + 4096;            // [d][k] hi    (ixt)
    short* Ktls = Kths + 4096;           // lo

    // XCD-chunked swizzle: 2 (b,h) per XCD
    const int bid = blockIdx.x;
    const int xcd = bid & 7;
    int bh, qt, ks, pidx;
    if (SPLIT) {
        const int idx = bid >> 3;            // 0..255
        bh = (xcd << 1) | (idx >> 7);
        const int rem = idx & 127;
        qt = rem >> 1;                       // 0..63
        ks = rem & 1;
        pidx = (bh * 64 + qt) * 2 + ks;
    } else {
        const int idx = bid >> 3;            // 0..127
        bh = (xcd << 1) | (idx >> 6);
        qt = idx & 63;
        ks = 0;
        pidx = 0;
    }
    const int b = bh >> 3, h = bh & 7;
    const int q0 = qt * 64;
    const int kt0 = SPLIT ? ks * 32 : 0;
    const int nkt = SPLIT ? 32 : 64;

    const int tid  = threadIdx.x;
    const int wave = tid >> 6, lane = tid & 63;
    const int lq   = lane & 31;
    const int hi   = lane >> 5;

    // ---- Q B-frags: pre-scaled, split hi/lo ----
    s16x8 qbh[4], qbl[4];
    {
        const int qrow = q0 + wave*32 + lq;
        const float* qp = Q + ((size_t)(b*N_ + qrow)) * D_ + h*HD_ + hi*8;
        #pragma unroll
        for (int s = 0; s < 4; ++s) {
            float4 a = *(const float4*)(qp + s*16);
            float4 c = *(const float4*)(qp + s*16 + 4);
            float v[8] = {a.x,a.y,a.z,a.w,c.x,c.y,c.z,c.w};
            #pragma unroll
            for (int j = 0; j < 8; ++j) {
                float xv = v[j] * SCL2;
                unsigned hh = bf16rtn(xv);
                float lo = xv - bf16tof(hh);
                qbh[s][j] = (short)hh;
                qbl[s][j] = (short)bf16rtn(lo);
            }
        }
    }

    f32x16 oacc[2] = {};
    float mrun = -1e30f, lrun = 0.f;

    // staging: 128 threads, each 8 rows x 4 cols
    const int br = tid >> 4, bc = tid & 15;
    s16x4 rh[8], rl[8];

    {   // prefetch tile kt0
        const size_t kbase = ((size_t)(b*N_ + kt0*64 + br*8)) * D_ + h*HD_ + bc*4;
        #pragma unroll
        for (int i = 0; i < 8; ++i) {
            rh[i] = *(const s16x4*)&Khi[kbase + (size_t)i * D_];
            rl[i] = *(const s16x4*)&Klo[kbase + (size_t)i * D_];
        }
    }

    for (int it = 0; it < nkt; ++it) {
        const int kt = kt0 + it;
        // ---- stage prefetched K tile (direct + transposed) ----
        #pragma unroll
        for (int i = 0; i < 8; ++i) {
            *(s16x4*)&Khs[ix16(br*8+i, bc*4)] = rh[i];
            *(s16x4*)&Kls[ix16(br*8+i, bc*4)] = rl[i];
        }
        #pragma unroll
        for (int half = 0; half < 2; ++half)
            #pragma unroll
            for (int j = 0; j < 4; ++j) {
                s16x4 th = { rh[half*4+0][j], rh[half*4+1][j], rh[half*4+2][j], rh[half*4+3][j] };
                s16x4 tl = { rl[half*4+0][j], rl[half*4+1][j], rl[half*4+2][j], rl[half*4+3][j] };
                *(s16x4*)&Kths[ixt(bc*4+j, br*8 + half*4)] = th;
                *(s16x4*)&Ktls[ixt(bc*4+j, br*8 + half*4)] = tl;
            }
        __syncthreads();

        // ---- prefetch next tile ----
        if (it < nkt - 1) {
            const size_t kbase = ((size_t)(b*N_ + (kt+1)*64 + br*8)) * D_ + h*HD_ + bc*4;
            #pragma unroll
            for (int i = 0; i < 8; ++i) {
                rh[i] = *(const s16x4*)&Khi[kbase + (size_t)i * D_];
                rl[i] = *(const s16x4*)&Klo[kbase + (size_t)i * D_];
            }
        }

        // ---- S^T = K Q' : D[k][q], bf16x3 ----
        f32x16 sacc[2] = {};
        __builtin_amdgcn_s_setprio(1);
        #pragma unroll
        for (int t = 0; t < 2; ++t) {
            #pragma unroll
            for (int s = 0; s < 4; ++s) {
                s16x8 ah = *(const s16x8*)&Khs[ix16(t*32 + lq, s*16 + hi*8)];
                s16x8 al = *(const s16x8*)&Kls[ix16(t*32 + lq, s*16 + hi*8)];
                sacc[t] = MFMA32(ah, qbh[s], sacc[t]);
                sacc[t] = MFMA32(ah, qbl[s], sacc[t]);
                sacc[t] = MFMA32(al, qbh[s], sacc[t]);
            }
        }
        __builtin_amdgcn_s_setprio(0);

        // ---- online softmax, lane-local, defer-max (THR=8, base-2) ----
        float tr[16];
        #pragma unroll
        for (int r = 0; r < 16; ++r) tr[r] = fmaxf(sacc[0][r], sacc[1][r]);
        #pragma unroll
        for (int st = 8; st >= 1; st >>= 1)
            #pragma unroll
            for (int r = 0; r < st; ++r) tr[r] = fmaxf(tr[r], tr[r + st]);
        float mt = fmaxf(tr[0], __shfl_xor(tr[0], 32));
        if (__any(mt > mrun + 8.0f)) {
            const float mn  = fmaxf(mrun, mt);
            const float al_ = __builtin_amdgcn_exp2f(mrun - mn);
            mrun = mn;
            lrun *= al_;
            #pragma unroll
            for (int dt = 0; dt < 2; ++dt)
                #pragma unroll
                for (int r = 0; r < 16; ++r)
                    oacc[dt][r] *= al_;
        }

        f32x16 p[2];
        #pragma unroll
        for (int t = 0; t < 2; ++t)
            #pragma unroll
            for (int r = 0; r < 16; ++r)
                p[t][r] = __builtin_amdgcn_exp2f(sacc[t][r] - mrun);
        #pragma unroll
        for (int r = 0; r < 16; ++r) tr[r] = p[0][r] + p[1][r];
        #pragma unroll
        for (int st = 8; st >= 1; st >>= 1)
            #pragma unroll
            for (int r = 0; r < st; ++r) tr[r] += tr[r + st];
        lrun += tr[0] + __shfl_xor(tr[0], 32);

        // ---- O^T += V^T P^T : per 16-k step, P assembled in-register ----
        __builtin_amdgcn_s_setprio(1);
        #pragma unroll
        for (int s = 0; s < 4; ++s) {
            const int tt = s >> 1, r0 = (s & 1) * 8;
            float ph[8], pl[8];
            #pragma unroll
            for (int j = 0; j < 8; ++j) {
                float pv = p[tt][r0 + j];
                float hf = __uint_as_float(__float_as_uint(pv) & 0xFFFF0000u);
                ph[j] = hf;
                pl[j] = pv - hf;
            }
            unsigned h0 = cvt_pk_bf16(ph[0], ph[1]);
            unsigned h1 = cvt_pk_bf16(ph[4], ph[5]);
            perm32swap(h0, h1);
            unsigned h2 = cvt_pk_bf16(ph[2], ph[3]);
            unsigned h3 = cvt_pk_bf16(ph[6], ph[7]);
            perm32swap(h2, h3);
            u32x4 wph = { h0, h2, h1, h3 };
            s16x8 pfh = __builtin_bit_cast(s16x8, wph);

            unsigned l0 = cvt_pk_bf16(pl[0], pl[1]);
            unsigned l1 = cvt_pk_bf16(pl[4], pl[5]);
            perm32swap(l0, l1);
            unsigned l2 = cvt_pk_bf16(pl[2], pl[3]);
            unsigned l3 = cvt_pk_bf16(pl[6], pl[7]);
            perm32swap(l2, l3);
            u32x4 wpl = { l0, l2, l1, l3 };
            s16x8 pfl = __builtin_bit_cast(s16x8, wpl);

            #pragma unroll
            for (int dt = 0; dt < 2; ++dt) {
                s16x8 vh = *(const s16x8*)&Kths[ixt(dt*32 + lq, s*16 + hi*8)];
                s16x8 vl = *(const s16x8*)&Ktls[ixt(dt*32 + lq, s*16 + hi*8)];
                oacc[dt] = MFMA32(vh, pfh, oacc[dt]);
                oacc[dt] = MFMA32(vl, pfh, oacc[dt]);
                oacc[dt] = MFMA32(vh, pfl, oacc[dt]);
            }
        }
        __builtin_amdgcn_s_setprio(0);
        __syncthreads();
    }

    if (SPLIT) {
        // ---- partial epilogue: raw O^T (units 2^(s-mrun)), plus m,l ----
        float* Op = Opart + (size_t)pidx * 4096;    // [64 d][64 q]
        #pragma unroll
        for (int dt = 0; dt < 2; ++dt)
            #pragma unroll
            for (int r = 0; r < 16; ++r) {
                const int d = dt*32 + (r & 3) + 8*(r >> 2) + 4*hi;
                Op[d*64 + wave*32 + lq] = oacc[dt][r];
            }
        if (hi == 0) {
            Ml[(size_t)pidx*128 + wave*32 + lq]      = mrun;
            Ml[(size_t)pidx*128 + 64 + wave*32 + lq] = lrun;
        }
    } else {
        // ---- final epilogue: O /= l; transpose via reused LDS ----
        const float inv = 1.0f / lrun;
        float* Os = (float*)smem;               // [64][64], 4-block XOR swizzle
        __syncthreads();
        #pragma unroll
        for (int dt = 0; dt < 2; ++dt)
            #pragma unroll
            for (int g = 0; g < 4; ++g) {
                f32x4 w;
                #pragma unroll
                for (int e = 0; e < 4; ++e)
                    w[e] = oacc[dt][g*4 + e] * inv;
                const int q = wave*32 + lq;
                const int dbase = dt*32 + g*8 + hi*4;
                *(f32x4*)&Os[q*64 + (dbase ^ (q & 28))] = w;
            }
        __syncthreads();
        #pragma unroll
        for (int rep = 0; rep < 8; ++rep) {
            const int row = (tid >> 4) + rep*8;
            const int c4  = (tid & 15) * 4;
            f32x4 w = *(const f32x4*)&Os[row*64 + (c4 ^ (row & 28))];
            *(f32x4*)&out[((size_t)(b*N_ + q0 + row)) * D_ + h*HD_ + c4] = w;
        }
    }
}

// ---------------------------------------------------------------------------
// Merge: combine the two KV-split partials, normalize, transpose, store.
// grid = 1024 (= bh*64 + qt), 256 threads.
// ---------------------------------------------------------------------------
__global__ __launch_bounds__(256) void merge_kernel(
    const float* __restrict__ Opart, const float* __restrict__ Ml,
    float* __restrict__ out)
{
    const int bid = blockIdx.x;
    const int bh = bid >> 6, qt = bid & 63;
    const int b = bh >> 3, h = bh & 7;
    const int q0 = qt * 64;
    const int p0 = bid * 2, p1 = bid * 2 + 1;

    const int tid = threadIdx.x;
    const int tq = tid & 63, dg = tid >> 6;     // 4 d-groups of 16

    const float m1 = Ml[(size_t)p0*128 + tq], l1 = Ml[(size_t)p0*128 + 64 + tq];
    const float m2 = Ml[(size_t)p1*128 + tq], l2 = Ml[(size_t)p1*128 + 64 + tq];
    const float m  = fmaxf(m1, m2);
    const float s1 = __builtin_amdgcn_exp2f(m1 - m);
    const float s2 = __builtin_amdgcn_exp2f(m2 - m);
    const float linv = 1.0f / (l1*s1 + l2*s2);

    __shared__ float T[64 * 65];
    const float* O1 = Opart + (size_t)p0 * 4096;
    const float* O2 = Opart + (size_t)p1 * 4096;
    #pragma unroll
    for (int i = 0; i < 16; ++i) {
        const int d = dg*16 + i;
        const float v = (O1[d*64 + tq]*s1 + O2[d*64 + tq]*s2) * linv;
        T[tq*65 + d] = v;
    }
    __syncthreads();

    const int row = tid >> 2;
    const int c0  = (tid & 3) * 16;
    #pragma unroll
    for (int g = 0; g < 4; ++g) {
        f32x4 w;
        #pragma unroll
        for (int e = 0; e < 4; ++e)
            w[e] = T[row*65 + c0 + g*4 + e];
        *(f32x4*)&out[((size_t)(b*N_ + q0 + row)) * D_ + h*HD_ + c0 + g*4] = w;
    }
}

extern "C" void kernel_launch(void* const* d_in, const int* in_sizes, int n_in,
                              void* d_out, int out_size, void* d_ws, size_t ws_size,
                              hipStream_t stream)
{
    const float* x  = (const float*)d_in[0];
    const float* Wq = (const float*)d_in[1];
    const float* bq = (const float*)d_in[2];
    const float* Wk = (const float*)d_in[3];
    const float* bk = (const float*)d_in[4];
    float* outp = (float*)d_out;

    // ws layout (bytes):
    //  [0,        16777216)  Qw fp32
    //  [16777216, 33554432)  Khi|Klo bf16
    //  [33554432, 52428800)  xh|xl|wqh|wql|wkh|wkl (split bufs, dead after proj)
    //  [33554432, 67108864)  Opart fp32  (ALIASES split bufs; written after proj)
    //  [67108864, 68157440)  Ml fp32
    char* wsb = (char*)d_ws;
    float* Qw  = (float*)wsb;
    short* Khi = (short*)(wsb + 16777216);
    short* Klo = Khi + 4194304;

    if (ws_size >= 52428800) {
        short* xh  = (short*)(wsb + 33554432);
        short* xl  = xh + 4194304;
        short* wqh = (short*)(wsb + 50331648);
        short* wql = wqh + 262144;
        short* wkh = wql + 262144;
        short* wkl = wkh + 262144;

        split_kernel<<<dim3(2304), dim3(256), 0, stream>>>(
            x, Wq, Wk, xh, xl, wqh, wql, wkh, wkl);
        proj_gemm<<<dim3(64, 4, 2), dim3(256), 0, stream>>>(
            xh, xl, wqh, wql, wkh, wkl, bq, bk, Qw, Khi, Klo);
    } else {
        dim3 gp(64, 4, 2);
        proj_kernel<<<gp, dim3(256), 0, stream>>>(x, Wq, bq, Wk, bk, Qw, Khi, Klo);
    }

    if (ws_size >= 68157440) {
        float* Opart = (float*)(wsb + 33554432);
        float* Ml    = (float*)(wsb + 67108864);
        attn_kernel<1><<<dim3(2048), dim3(128), 0, stream>>>(
            Qw, Khi, Klo, outp, Opart, Ml);
        merge_kernel<<<dim3(1024), dim3(256), 0, stream>>>(Opart, Ml, outp);
    } else {
        attn_kernel<0><<<dim3(1024), dim3(128), 0, stream>>>(
            Qw, Khi, Klo, outp, nullptr, nullptr);
    }
}

// Round 8
// 291.830 us; speedup vs baseline: 1.3188x; 1.3188x over previous
//
#include <hip/hip_runtime.h>

#define B_  2
#define N_  4096
#define D_  512
#define H_  8
#define HD_ 64
// (D^-0.5) * log2(e): fold softmax scale AND exp->exp2 conversion into Q
#define SCL2 (0.04419417382415922f * 1.4426950408889634f)

typedef float  f32x4  __attribute__((ext_vector_type(4)));
typedef float  f32x16 __attribute__((ext_vector_type(16)));
typedef short  s16x8  __attribute__((ext_vector_type(8)));
typedef short  s16x4  __attribute__((ext_vector_type(4)));
typedef unsigned int u32x4 __attribute__((ext_vector_type(4)));

#define MFMA16(a,b,c) __builtin_amdgcn_mfma_f32_16x16x32_bf16((a),(b),(c),0,0,0)
#define MFMA32(a,b,c) __builtin_amdgcn_mfma_f32_32x32x16_bf16((a),(b),(c),0,0,0)

__device__ __forceinline__ unsigned bf16rtn(float x){
    unsigned u = __float_as_uint(x);
    return (u + 0x7FFFu + ((u >> 16) & 1u)) >> 16;
}
__device__ __forceinline__ float bf16tof(unsigned h){
    return __uint_as_float(h << 16);
}
__device__ __forceinline__ unsigned cvt_pk_bf16(float lo, float hi){
    unsigned r;
    asm("v_cvt_pk_bf16_f32 %0, %1, %2" : "=v"(r) : "v"(lo), "v"(hi));
    return r;
}
__device__ __forceinline__ void perm32swap(unsigned &a, unsigned &b){
    asm volatile("v_permlane32_swap_b32 %0, %1" : "+v"(a), "+v"(b));
}
// direct [R][64] bf16: XOR-swizzle 8-elem (16B) blocks with row&7
__device__ __forceinline__ int ix16(int r, int c){
    return (r << 6) + ((((c >> 3) ^ (r & 7)) << 3) | (c & 7));
}
// transposed [64 d][128 k] bf16: block XOR carries 4 bits of d so that
// per-instruction transpose WRITES (d = 4*bc+j, j fixed) span all 16 blocks
// -> 4 lanes/bank (wave64 minimum). Reads verified min too.
__device__ __forceinline__ int ixt2(int r, int c){
    return (r << 7) + ((((c >> 3) ^ ((r >> 2) & 15)) << 3) | (c & 7));
}

// ---------------------------------------------------------------------------
// Split pass: fp32 -> (bf16 hi, bf16 lo) for x, Wq, Wk. Pure streaming.
// ---------------------------------------------------------------------------
__global__ __launch_bounds__(256) void split_kernel(
    const float* __restrict__ x, const float* __restrict__ Wq, const float* __restrict__ Wk,
    short* __restrict__ xh, short* __restrict__ xl,
    short* __restrict__ wqh, short* __restrict__ wql,
    short* __restrict__ wkh, short* __restrict__ wkl)
{
    const int bid = blockIdx.x;
    const float* src; short* dh; short* dl; size_t base;
    if (bid < 2048)      { src = x;  dh = xh;  dl = xl;  base = (size_t)bid * 2048; }
    else if (bid < 2176) { src = Wq; dh = wqh; dl = wql; base = (size_t)(bid - 2048) * 2048; }
    else                 { src = Wk; dh = wkh; dl = wkl; base = (size_t)(bid - 2176) * 2048; }

    const size_t off = base + (size_t)threadIdx.x * 8;
    float4 a = *(const float4*)&src[off];
    float4 c = *(const float4*)&src[off + 4];
    float v[8] = {a.x,a.y,a.z,a.w, c.x,c.y,c.z,c.w};
    s16x8 oh, ol;
    #pragma unroll
    for (int j = 0; j < 8; ++j) {
        unsigned hh = bf16rtn(v[j]);
        float lo = v[j] - bf16tof(hh);
        unsigned ll = bf16rtn(lo);
        oh[j] = (short)hh; ol[j] = (short)ll;
    }
    *(s16x8*)&dh[off] = oh;
    *(s16x8*)&dl[off] = ol;
}

// ---------------------------------------------------------------------------
// Projection GEMM on MFMA, bf16x3 split precision. (unchanged)
// ---------------------------------------------------------------------------
__global__ __launch_bounds__(256, 2) void proj_gemm(
    const short* __restrict__ xh, const short* __restrict__ xl,
    const short* __restrict__ wqh, const short* __restrict__ wql,
    const short* __restrict__ wkh, const short* __restrict__ wkl,
    const float* __restrict__ bq, const float* __restrict__ bk,
    float* __restrict__ Qout, short* __restrict__ Khi, short* __restrict__ Klo)
{
    __shared__ short Ah[8192], Al[8192], Bh[8192], Bl[8192];   // [128][64] ix16

    const short* gWh  = blockIdx.z ? wkh : wqh;
    const short* gWl  = blockIdx.z ? wkl : wql;
    const float* bias = blockIdx.z ? bk  : bq;

    const int m0 = blockIdx.x * 128;
    const int e0 = blockIdx.y * 128;
    const int tid = threadIdx.x;
    const int wave = tid >> 6, lane = tid & 63;
    const int lr = lane & 15, lg = lane >> 4;

    int srow[4], scol[4];
    #pragma unroll
    for (int s = 0; s < 4; ++s) {
        int slot = s * 256 + tid;
        srow[s] = slot >> 3;
        scol[s] = (slot & 7) << 3;
    }

    f32x4 acc[2][8] = {};
    s16x8 pah[4], pal[4], pbh[4], pbl[4];

    #pragma unroll
    for (int s = 0; s < 4; ++s) {
        size_t ao = (size_t)(m0 + srow[s]) * D_ + scol[s];
        size_t bo = (size_t)(e0 + srow[s]) * D_ + scol[s];
        pah[s] = *(const s16x8*)&xh[ao];  pal[s] = *(const s16x8*)&xl[ao];
        pbh[s] = *(const s16x8*)&gWh[bo]; pbl[s] = *(const s16x8*)&gWl[bo];
    }

    for (int kt = 0; kt < 8; ++kt) {
        if (kt) __syncthreads();
        #pragma unroll
        for (int s = 0; s < 4; ++s) {
            int d = ix16(srow[s], scol[s]);
            *(s16x8*)&Ah[d] = pah[s];  *(s16x8*)&Al[d] = pal[s];
            *(s16x8*)&Bh[d] = pbh[s];  *(s16x8*)&Bl[d] = pbl[s];
        }
        __syncthreads();
        if (kt < 7) {
            const int k0 = (kt + 1) * 64;
            #pragma unroll
            for (int s = 0; s < 4; ++s) {
                size_t ao = (size_t)(m0 + srow[s]) * D_ + k0 + scol[s];
                size_t bo = (size_t)(e0 + srow[s]) * D_ + k0 + scol[s];
                pah[s] = *(const s16x8*)&xh[ao];  pal[s] = *(const s16x8*)&xl[ao];
                pbh[s] = *(const s16x8*)&gWh[bo]; pbl[s] = *(const s16x8*)&gWl[bo];
            }
        }
        __builtin_amdgcn_s_setprio(1);
        #pragma unroll
        for (int ks = 0; ks < 2; ++ks) {
            s16x8 afh[2], afl[2];
            #pragma unroll
            for (int f = 0; f < 2; ++f) {
                int a = ix16(wave*32 + f*16 + lr, ks*32 + lg*8);
                afh[f] = *(const s16x8*)&Ah[a];
                afl[f] = *(const s16x8*)&Al[a];
            }
            #pragma unroll
            for (int t = 0; t < 8; ++t) {
                int bA = ix16(t*16 + lr, ks*32 + lg*8);
                s16x8 bfh = *(const s16x8*)&Bh[bA];
                s16x8 bfl = *(const s16x8*)&Bl[bA];
                #pragma unroll
                for (int f = 0; f < 2; ++f) {
                    acc[f][t] = MFMA16(afh[f], bfh, acc[f][t]);
                    acc[f][t] = MFMA16(afh[f], bfl, acc[f][t]);
                    acc[f][t] = MFMA16(afl[f], bfh, acc[f][t]);
                }
            }
        }
        __builtin_amdgcn_s_setprio(0);
    }

    float bb[8];
    #pragma unroll
    for (int t = 0; t < 8; ++t) bb[t] = bias[e0 + t*16 + lr];

    if (blockIdx.z == 0) {
        #pragma unroll
        for (int f = 0; f < 2; ++f)
            #pragma unroll
            for (int t = 0; t < 8; ++t)
                #pragma unroll
                for (int r = 0; r < 4; ++r) {
                    int row = m0 + wave*32 + f*16 + lg*4 + r;
                    Qout[(size_t)row * D_ + e0 + t*16 + lr] = acc[f][t][r] + bb[t];
                }
    } else {
        #pragma unroll
        for (int f = 0; f < 2; ++f)
            #pragma unroll
            for (int t = 0; t < 8; ++t)
                #pragma unroll
                for (int r = 0; r < 4; ++r) {
                    int row = m0 + wave*32 + f*16 + lg*4 + r;
                    float v = acc[f][t][r] + bb[t];
                    unsigned hh = bf16rtn(v);
                    float lo = v - bf16tof(hh);
                    unsigned ll = bf16rtn(lo);
                    size_t o = (size_t)row * D_ + e0 + t*16 + lr;
                    Khi[o] = (short)hh;
                    Klo[o] = (short)ll;
                }
    }
}

// ---------------------------------------------------------------------------
// FALLBACK projection (fp32 vector path) — only if ws_size is too small.
// ---------------------------------------------------------------------------
__global__ __launch_bounds__(256) void proj_kernel(
    const float* __restrict__ x,
    const float* __restrict__ Wq, const float* __restrict__ bq,
    const float* __restrict__ Wk, const float* __restrict__ bk,
    float* __restrict__ Qout, short* __restrict__ Khi, short* __restrict__ Klo)
{
    const float* W    = blockIdx.z ? Wk : Wq;
    const float* bias = blockIdx.z ? bk : bq;

    const int m0 = blockIdx.x * 128;
    const int e0 = blockIdx.y * 128;

    __shared__ float Xs[128][36];
    __shared__ float Ws[128 * 36];

    const int tid = threadIdx.x;
    const int tx = tid & 15, ty = tid >> 4;

    float acc[8][8] = {};

    for (int k0 = 0; k0 < D_; k0 += 32) {
        #pragma unroll
        for (int s = 0; s < 4; ++s) {
            int slot = s * 256 + tid;
            int r  = slot >> 3;
            int c4 = (slot & 7) << 2;
            *(float4*)&Xs[r][c4] = *(const float4*)&x[(size_t)(m0 + r) * D_ + k0 + c4];
            int wblk = ((c4 >> 2) ^ (r >> 3)) & 7;
            *(float4*)&Ws[r * 36 + wblk * 4] = *(const float4*)&W[(size_t)(e0 + r) * D_ + k0 + c4];
        }
        __syncthreads();
        #pragma unroll
        for (int k = 0; k < 32; k += 4) {
            float4 xa[8], wb[8];
            #pragma unroll
            for (int i = 0; i < 8; ++i) xa[i] = *(float4*)&Xs[ty*8+i][k];
            #pragma unroll
            for (int j = 0; j < 8; ++j) {
                int row = tx*8 + j;
                int blk = ((k >> 2) ^ (row >> 3)) & 7;
                wb[j] = *(float4*)&Ws[row * 36 + blk * 4];
            }
            #pragma unroll
            for (int i = 0; i < 8; ++i)
                #pragma unroll
                for (int j = 0; j < 8; ++j)
                    acc[i][j] += xa[i].x*wb[j].x + xa[i].y*wb[j].y
                               + xa[i].z*wb[j].z + xa[i].w*wb[j].w;
        }
        __syncthreads();
    }

    const float4 bv0 = *(const float4*)&bias[e0 + tx*8];
    const float4 bv1 = *(const float4*)&bias[e0 + tx*8 + 4];
    const float bj[8] = {bv0.x,bv0.y,bv0.z,bv0.w, bv1.x,bv1.y,bv1.z,bv1.w};

    if (blockIdx.z == 0) {
        #pragma unroll
        for (int i = 0; i < 8; ++i) {
            float o[8];
            #pragma unroll
            for (int j = 0; j < 8; ++j) o[j] = acc[i][j] + bj[j];
            size_t off = (size_t)(m0 + ty*8 + i) * D_ + e0 + tx*8;
            *(float4*)&Qout[off]     = *(float4*)&o[0];
            *(float4*)&Qout[off + 4] = *(float4*)&o[4];
        }
    } else {
        #pragma unroll
        for (int i = 0; i < 8; ++i) {
            s16x8 oh, ol;
            #pragma unroll
            for (int j = 0; j < 8; ++j) {
                float v = acc[i][j] + bj[j];
                unsigned hh = bf16rtn(v);
                float lo = v - bf16tof(hh);
                unsigned ll = bf16rtn(lo);
                oh[j] = (short)hh; ol[j] = (short)ll;
            }
            size_t off = (size_t)(m0 + ty*8 + i) * D_ + e0 + tx*8;
            *(s16x8*)&Khi[off] = oh;
            *(s16x8*)&Klo[off] = ol;
        }
    }
}

// ---------------------------------------------------------------------------
// Flash attention, 32x32x16 MFMA, swapped operands, V = K.
// QBLK=128 (4 waves x 32 q), KVBLK=128 (32 iters, 2 barriers each),
// conflict-min swizzles, defer-max, in-register P via cvt_pk+permlane.
// ---------------------------------------------------------------------------
__global__ __launch_bounds__(256, 2) void attn_kernel(
    const float* __restrict__ Q,
    const short* __restrict__ Khi, const short* __restrict__ Klo,
    float* __restrict__ out)
{
    __shared__ __align__(16) char smem[65536];
    short* Khs  = (short*)smem;          // [128 k][64 d] hi  (ix16)
    short* Kls  = Khs + 8192;            // lo
    short* Kths = Kls + 8192;            // [64 d][128 k] hi  (ixt2)
    short* Ktls = Kths + 8192;           // lo

    // XCD-chunked swizzle: 2 (b,h) per XCD
    const int bid = blockIdx.x;
    const int xcd = bid & 7, kk = bid >> 3;
    const int bh  = (xcd << 1) | (kk >> 5);
    const int qt  = kk & 31;
    const int b = bh >> 3, h = bh & 7;
    const int q0 = qt * 128;

    const int tid  = threadIdx.x;
    const int wave = tid >> 6, lane = tid & 63;
    const int lq   = lane & 31;
    const int hi   = lane >> 5;

    // ---- Q B-frags: pre-scaled, split hi/lo ----
    s16x8 qbh[4], qbl[4];
    {
        const int qrow = q0 + wave*32 + lq;
        const float* qp = Q + ((size_t)(b*N_ + qrow)) * D_ + h*HD_ + hi*8;
        #pragma unroll
        for (int s = 0; s < 4; ++s) {
            float4 a = *(const float4*)(qp + s*16);
            float4 c = *(const float4*)(qp + s*16 + 4);
            float v[8] = {a.x,a.y,a.z,a.w,c.x,c.y,c.z,c.w};
            #pragma unroll
            for (int j = 0; j < 8; ++j) {
                float xv = v[j] * SCL2;
                unsigned hh = bf16rtn(xv);
                float lo = xv - bf16tof(hh);
                qbh[s][j] = (short)hh;
                qbl[s][j] = (short)bf16rtn(lo);
            }
        }
    }

    f32x16 oacc[2] = {};
    float mrun = -1e30f, lrun = 0.f;

    // staging: thread covers rows rg*8..+7 (k), cols bc*4..+3 (d)
    const int rg = tid >> 4, bc = tid & 15;
    s16x4 rh[8], rl[8];

    {   // prefetch tile 0
        const size_t kbase = ((size_t)(b*N_ + rg*8)) * D_ + h*HD_ + bc*4;
        #pragma unroll
        for (int i = 0; i < 8; ++i) {
            rh[i] = *(const s16x4*)&Khi[kbase + (size_t)i * D_];
            rl[i] = *(const s16x4*)&Klo[kbase + (size_t)i * D_];
        }
    }

    for (int kt = 0; kt < 32; ++kt) {
        // ---- stage prefetched 128-key tile (direct + transposed) ----
        #pragma unroll
        for (int i = 0; i < 8; ++i) {
            *(s16x4*)&Khs[ix16(rg*8+i, bc*4)] = rh[i];
            *(s16x4*)&Kls[ix16(rg*8+i, bc*4)] = rl[i];
        }
        #pragma unroll
        for (int j = 0; j < 4; ++j) {
            s16x8 th, tl;
            #pragma unroll
            for (int i = 0; i < 8; ++i) { th[i] = rh[i][j]; tl[i] = rl[i][j]; }
            *(s16x8*)&Kths[ixt2(bc*4+j, rg*8)] = th;
            *(s16x8*)&Ktls[ixt2(bc*4+j, rg*8)] = tl;
        }
        __syncthreads();

        // ---- prefetch next 128-key tile (hides under compute) ----
        if (kt < 31) {
            const size_t kbase = ((size_t)(b*N_ + (kt+1)*128 + rg*8)) * D_ + h*HD_ + bc*4;
            #pragma unroll
            for (int i = 0; i < 8; ++i) {
                rh[i] = *(const s16x4*)&Khi[kbase + (size_t)i * D_];
                rl[i] = *(const s16x4*)&Klo[kbase + (size_t)i * D_];
            }
        }

        // ---- S^T = K Q' : D[k][q], 4 k-tiles of 32, bf16x3 ----
        f32x16 sacc[4] = {};
        __builtin_amdgcn_s_setprio(1);
        #pragma unroll
        for (int t = 0; t < 4; ++t) {
            #pragma unroll
            for (int s = 0; s < 4; ++s) {
                s16x8 ah = *(const s16x8*)&Khs[ix16(t*32 + lq, s*16 + hi*8)];
                s16x8 al = *(const s16x8*)&Kls[ix16(t*32 + lq, s*16 + hi*8)];
                sacc[t] = MFMA32(ah, qbh[s], sacc[t]);
                sacc[t] = MFMA32(ah, qbl[s], sacc[t]);
                sacc[t] = MFMA32(al, qbh[s], sacc[t]);
            }
        }
        __builtin_amdgcn_s_setprio(0);

        // ---- online softmax, lane-local, defer-max (THR=8, base-2) ----
        float tr[16];
        #pragma unroll
        for (int r = 0; r < 16; ++r)
            tr[r] = fmaxf(fmaxf(sacc[0][r], sacc[1][r]),
                          fmaxf(sacc[2][r], sacc[3][r]));
        #pragma unroll
        for (int st = 8; st >= 1; st >>= 1)
            #pragma unroll
            for (int r = 0; r < st; ++r) tr[r] = fmaxf(tr[r], tr[r + st]);
        float mt = fmaxf(tr[0], __shfl_xor(tr[0], 32));
        if (__any(mt > mrun + 8.0f)) {
            const float mn  = fmaxf(mrun, mt);
            const float al_ = __builtin_amdgcn_exp2f(mrun - mn);
            mrun = mn;
            lrun *= al_;
            #pragma unroll
            for (int dt = 0; dt < 2; ++dt)
                #pragma unroll
                for (int r = 0; r < 16; ++r)
                    oacc[dt][r] *= al_;
        }

        f32x16 p[4];
        #pragma unroll
        for (int t = 0; t < 4; ++t)
            #pragma unroll
            for (int r = 0; r < 16; ++r)
                p[t][r] = __builtin_amdgcn_exp2f(sacc[t][r] - mrun);
        #pragma unroll
        for (int r = 0; r < 16; ++r)
            tr[r] = (p[0][r] + p[1][r]) + (p[2][r] + p[3][r]);
        #pragma unroll
        for (int st = 8; st >= 1; st >>= 1)
            #pragma unroll
            for (int r = 0; r < st; ++r) tr[r] += tr[r + st];
        lrun += tr[0] + __shfl_xor(tr[0], 32);

        // ---- O^T += V^T P^T : 8 k-16 steps, P assembled in-register ----
        __builtin_amdgcn_s_setprio(1);
        #pragma unroll
        for (int s = 0; s < 8; ++s) {
            const int tt = s >> 1, r0 = (s & 1) * 8;
            float ph[8], pl[8];
            #pragma unroll
            for (int j = 0; j < 8; ++j) {
                float pv = p[tt][r0 + j];
                float hf = __uint_as_float(__float_as_uint(pv) & 0xFFFF0000u);
                ph[j] = hf;
                pl[j] = pv - hf;
            }
            unsigned h0 = cvt_pk_bf16(ph[0], ph[1]);
            unsigned h1 = cvt_pk_bf16(ph[4], ph[5]);
            perm32swap(h0, h1);
            unsigned h2 = cvt_pk_bf16(ph[2], ph[3]);
            unsigned h3 = cvt_pk_bf16(ph[6], ph[7]);
            perm32swap(h2, h3);
            u32x4 wph = { h0, h2, h1, h3 };
            s16x8 pfh = __builtin_bit_cast(s16x8, wph);

            unsigned l0 = cvt_pk_bf16(pl[0], pl[1]);
            unsigned l1 = cvt_pk_bf16(pl[4], pl[5]);
            perm32swap(l0, l1);
            unsigned l2 = cvt_pk_bf16(pl[2], pl[3]);
            unsigned l3 = cvt_pk_bf16(pl[6], pl[7]);
            perm32swap(l2, l3);
            u32x4 wpl = { l0, l2, l1, l3 };
            s16x8 pfl = __builtin_bit_cast(s16x8, wpl);

            #pragma unroll
            for (int dt = 0; dt < 2; ++dt) {
                s16x8 vh = *(const s16x8*)&Kths[ixt2(dt*32 + lq, s*16 + hi*8)];
                s16x8 vl = *(const s16x8*)&Ktls[ixt2(dt*32 + lq, s*16 + hi*8)];
                oacc[dt] = MFMA32(vh, pfh, oacc[dt]);
                oacc[dt] = MFMA32(vl, pfh, oacc[dt]);
                oacc[dt] = MFMA32(vh, pfl, oacc[dt]);
            }
        }
        __builtin_amdgcn_s_setprio(0);
        __syncthreads();
    }

    // ---- epilogue: O /= l; transpose via reused LDS; coalesced store ----
    const float inv = 1.0f / lrun;
    float* Os = (float*)smem;               // [128][64], 4-block XOR swizzle
    #pragma unroll
    for (int dt = 0; dt < 2; ++dt)
        #pragma unroll
        for (int g = 0; g < 4; ++g) {
            f32x4 w;
            #pragma unroll
            for (int e = 0; e < 4; ++e)
                w[e] = oacc[dt][g*4 + e] * inv;
            const int q = wave*32 + lq;
            const int dbase = dt*32 + g*8 + hi*4;
            *(f32x4*)&Os[q*64 + (dbase ^ (q & 28))] = w;
        }
    __syncthreads();
    #pragma unroll
    for (int rep = 0; rep < 8; ++rep) {
        const int row = (tid >> 4) + rep*16;
        const int c4  = (tid & 15) * 4;
        f32x4 w = *(const f32x4*)&Os[row*64 + (c4 ^ (row & 28))];
        *(f32x4*)&out[((size_t)(b*N_ + q0 + row)) * D_ + h*HD_ + c4] = w;
    }
}

extern "C" void kernel_launch(void* const* d_in, const int* in_sizes, int n_in,
                              void* d_out, int out_size, void* d_ws, size_t ws_size,
                              hipStream_t stream)
{
    const float* x  = (const float*)d_in[0];
    const float* Wq = (const float*)d_in[1];
    const float* bq = (const float*)d_in[2];
    const float* Wk = (const float*)d_in[3];
    const float* bk = (const float*)d_in[4];
    float* outp = (float*)d_out;

    // ws layout (bytes):
    //  [0,        16777216)  Qw fp32
    //  [16777216, 33554432)  Khi|Klo bf16
    //  [33554432, 52428800)  xh|xl|wqh|wql|wkh|wkl (split bufs, dead after proj)
    char* wsb = (char*)d_ws;
    float* Qw  = (float*)wsb;
    short* Khi = (short*)(wsb + 16777216);
    short* Klo = Khi + 4194304;

    if (ws_size >= 52428800) {
        short* xh  = (short*)(wsb + 33554432);
        short* xl  = xh + 4194304;
        short* wqh = (short*)(wsb + 50331648);
        short* wql = wqh + 262144;
        short* wkh = wql + 262144;
        short* wkl = wkh + 262144;

        split_kernel<<<dim3(2304), dim3(256), 0, stream>>>(
            x, Wq, Wk, xh, xl, wqh, wql, wkh, wkl);
        proj_gemm<<<dim3(64, 4, 2), dim3(256), 0, stream>>>(
            xh, xl, wqh, wql, wkh, wkl, bq, bk, Qw, Khi, Klo);
    } else {
        dim3 gp(64, 4, 2);
        proj_kernel<<<gp, dim3(256), 0, stream>>>(x, Wq, bq, Wk, bk, Qw, Khi, Klo);
    }

    attn_kernel<<<dim3(512), dim3(256), 0, stream>>>(Qw, Khi, Klo, outp);
}